// Round 1
// 527.404 us; speedup vs baseline: 1.0397x; 1.0397x over previous
//
#include <hip/hip_runtime.h>
#include <hip/hip_bf16.h>
#include <stdint.h>

#define M_DIM 4096
#define K_DIM 4096
#define N_DIM 2048
#define B_DIM 4
#define NNZ_PER_ROW 409
#define NNZ_TOT (M_DIM * NNZ_PER_ROW)

typedef unsigned short u16;
typedef short short8 __attribute__((ext_vector_type(8)));
typedef float f32x4 __attribute__((ext_vector_type(4)));

__device__ __forceinline__ u16 f2bf(float f) {
    __hip_bfloat16 h = __float2bfloat16(f);
    u16 s;
    __builtin_memcpy(&s, &h, 2);
    return s;
}

// async global->LDS, 16 bytes per lane; LDS dest = wave-uniform base + lane*16
__device__ __forceinline__ void lds16(const u16* g, u16* l) {
    __builtin_amdgcn_global_load_lds(
        (__attribute__((address_space(1))) void*)g,
        (__attribute__((address_space(3))) void*)l,
        16, 0, 0);
}

// ---------------------------------------------------------------------------
// Kernel 1: x fp32 -> bf16. Each lane: 32 B read (2x float4), 16 B write.
// ---------------------------------------------------------------------------
__global__ void cvt_x(const float* __restrict__ in, u16* __restrict__ out) {
    int i = blockIdx.x * blockDim.x + threadIdx.x;  // 8 elements per thread
    float4 a = reinterpret_cast<const float4*>(in)[2 * i];
    float4 b = reinterpret_cast<const float4*>(in)[2 * i + 1];
    union { u16 u[8]; uint4 v; } o;
    o.u[0] = f2bf(a.x); o.u[1] = f2bf(a.y); o.u[2] = f2bf(a.z); o.u[3] = f2bf(a.w);
    o.u[4] = f2bf(b.x); o.u[5] = f2bf(b.y); o.u[6] = f2bf(b.z); o.u[7] = f2bf(b.w);
    reinterpret_cast<uint4*>(out)[i] = o.v;
}

// ---------------------------------------------------------------------------
// Kernel 2: CSR row -> dense bf16 W row, one block per row.
// fp32 accumulate in LDS (duplicates via atomicAdd, matching .add semantics),
// then fully-coalesced 16B stores. No global memset needed.
// ---------------------------------------------------------------------------
__global__ __launch_bounds__(256) void scatter_w(const float* __restrict__ vals,
                                                 const int* __restrict__ cols,
                                                 u16* __restrict__ W) {
    __shared__ float row[K_DIM];  // 16 KB
    const int t = threadIdx.x;
    const int m = blockIdx.x;
#pragma unroll
    for (int c = t; c < K_DIM; c += 256) row[c] = 0.0f;
    __syncthreads();
    const int base = m * NNZ_PER_ROW;
    for (int j = t; j < NNZ_PER_ROW; j += 256)
        atomicAdd(&row[cols[base + j]], vals[base + j]);
    __syncthreads();
    u16* Wr = W + (size_t)m * K_DIM + t * 16;
#pragma unroll
    for (int h = 0; h < 2; ++h) {
        union { u16 u[8]; uint4 v; } o;
#pragma unroll
        for (int e = 0; e < 8; ++e) o.u[e] = f2bf(row[t * 16 + h * 8 + e]);
        reinterpret_cast<uint4*>(Wr)[h] = o.v;
    }
}

// ---------------------------------------------------------------------------
// Kernel 3: NT GEMM, 256x256 tile, BK=64, 8-phase counted-vmcnt schedule
// (T2+T3+T4+T5 per the 256^2 8-phase template).
//   8 waves = 2(M) x 4(N); each wave owns 128x64 of C as 8x4 fragments.
//   LDS: sA/sB [2 buf][256 rows][64 cols] bf16 = 128 KiB total. Even K-tiles
//   in buf0, odd in buf1. Each buffer = 2 half-tiles (rows 0-127 / 128-255).
//   Quadrant order (mq,nq): (0,0)(0,1)(1,0)(1,1) -> half free-schedule:
//   A0 after ph2, B0 after ph3, A1/B1 after ph4. Stage schedule (iter t=2i):
//     p1: (t+1).A1->buf1   p2: (t+1).B1->buf1   p3: (t+2).A0->buf0
//     p4: (t+2).B0->buf0 +vmcnt(4)  [guarantees t+1 landed]
//     p5: (t+2).A1->buf0   p6: (t+2).B1->buf0   p7: (t+3).A0->buf1
//     p8: (t+3).B0->buf1 +vmcnt(4)  [guarantees t+2 landed]
//   Every stage targets a half whose last reader finished >=1 barrier earlier.
//   vmcnt never drains to 0 in the main loop: 2 half-tiles (4 loads) stay in
//   flight across every barrier.
//   Row swizzle (chunk c of row r stored at c ^ (r&7), 16B chunks) applied via
//   pre-swizzled GLOBAL source + swizzled ds_read offsets; LDS dest stays
//   linear as global_load_lds requires. Measured 0 bank conflicts before.
// ---------------------------------------------------------------------------
#define NOPV ((void)0)
#define VM4 asm volatile("s_waitcnt vmcnt(4)" ::: "memory")
#define VM0 asm volatile("s_waitcnt vmcnt(0)" ::: "memory")

#define STAGE_A(BUF, H, KT) do {                                                  \
    lds16(Ag + (size_t)((H) * 128 +  0) * K_DIM + (size_t)(KT) * 64,              \
          &sA[BUF][(H) * 128 +  0 + wave * 8][0]);                                \
    lds16(Ag + (size_t)((H) * 128 + 64) * K_DIM + (size_t)(KT) * 64,              \
          &sA[BUF][(H) * 128 + 64 + wave * 8][0]);                                \
} while (0)

#define STAGE_B(BUF, H, KT) do {                                                  \
    lds16(Bg + (size_t)((H) * 128 +  0) * K_DIM + (size_t)(KT) * 64,              \
          &sB[BUF][(H) * 128 +  0 + wave * 8][0]);                                \
    lds16(Bg + (size_t)((H) * 128 + 64) * K_DIM + (size_t)(KT) * 64,              \
          &sB[BUF][(H) * 128 + 64 + wave * 8][0]);                                \
} while (0)

// Phase: ds_read fragment subtile -> issue stage -> barrier -> lgkm(0) ->
// setprio(1) MFMA x16 setprio(0) -> [vmcnt] -> barrier.
#define PHASE(BUF, MQ, NQ, STAGE_STMT, WAIT_STMT) do {                            \
    short8 a0_[4], a1_[4], b0_[2], b1_[2];                                        \
    _Pragma("unroll")                                                             \
    for (int i_ = 0; i_ < 4; ++i_) {                                              \
        const u16* p_ = &sA[BUF][(MQ) * 128 + wm * 64 + i_ * 16 + fm][0];         \
        a0_[i_] = *(const short8*)(p_ + c0);                                      \
        a1_[i_] = *(const short8*)(p_ + c1);                                      \
    }                                                                             \
    _Pragma("unroll")                                                             \
    for (int j_ = 0; j_ < 2; ++j_) {                                              \
        const u16* p_ = &sB[BUF][(NQ) * 128 + wn * 32 + j_ * 16 + fm][0];         \
        b0_[j_] = *(const short8*)(p_ + c0);                                      \
        b1_[j_] = *(const short8*)(p_ + c1);                                      \
    }                                                                             \
    STAGE_STMT;                                                                   \
    asm volatile("" ::: "memory");                                                \
    __builtin_amdgcn_s_barrier();                                                 \
    asm volatile("s_waitcnt lgkmcnt(0)" ::: "memory");                            \
    __builtin_amdgcn_sched_barrier(0);                                            \
    __builtin_amdgcn_s_setprio(1);                                                \
    _Pragma("unroll")                                                             \
    for (int i_ = 0; i_ < 4; ++i_) {                                              \
        _Pragma("unroll")                                                         \
        for (int j_ = 0; j_ < 2; ++j_) {                                          \
            acc[(MQ) * 4 + i_][(NQ) * 2 + j_] =                                   \
                __builtin_amdgcn_mfma_f32_16x16x32_bf16(                          \
                    a0_[i_], b0_[j_], acc[(MQ) * 4 + i_][(NQ) * 2 + j_], 0, 0, 0);\
            acc[(MQ) * 4 + i_][(NQ) * 2 + j_] =                                   \
                __builtin_amdgcn_mfma_f32_16x16x32_bf16(                          \
                    a1_[i_], b1_[j_], acc[(MQ) * 4 + i_][(NQ) * 2 + j_], 0, 0, 0);\
        }                                                                         \
    }                                                                             \
    __builtin_amdgcn_s_setprio(0);                                                \
    WAIT_STMT;                                                                    \
    asm volatile("" ::: "memory");                                                \
    __builtin_amdgcn_s_barrier();                                                 \
} while (0)

__global__ __launch_bounds__(512, 2) void gemm_bt(
    const u16* __restrict__ A,
    const u16* __restrict__ Bt,
    float* __restrict__ C) {
    __shared__ __align__(16) u16 sA[2][256][64];  // 64 KB
    __shared__ __align__(16) u16 sB[2][256][64];  // 64 KB

    const int tid  = threadIdx.x;
    const int wave = tid >> 6;
    const int lane = tid & 63;
    const int wm = wave >> 2;     // 0..1 (M)
    const int wn = wave & 3;      // 0..3 (N)

    // XCD-aware bijective swizzle of the 128 (m,n) tiles per batch
    int wg  = blockIdx.y * 8 + blockIdx.x;          // 0..127
    int swz = (wg & 7) * 16 + (wg >> 3);
    const int bn0 = (swz & 7) * 256;
    const int bm0 = (swz >> 3) * 256;
    const int bat = blockIdx.z;

    // staging: lane covers row (lane>>3) of an 8-row group; global 16B chunk
    // is (lane&7) ^ (lane>>3)  [pre-swizzled source, linear LDS dest]
    const int slr = lane >> 3;
    const int slc = ((lane & 7) ^ slr) * 8;
    const u16* Ag = A + (size_t)(bm0 + wave * 8 + slr) * K_DIM + slc;
    const u16* Bg = Bt + (size_t)bat * N_DIM * K_DIM
                      + (size_t)(bn0 + wave * 8 + slr) * K_DIM + slc;

    // fragment decomposition (identical to verified 128^2 kernel)
    const int fm   = lane & 15;
    const int quad = lane >> 4;
    const int c0   = ((quad     ^ (fm & 7)) * 8);   // K-step 0 chunk (elems)
    const int c1   = (((quad + 4) ^ (fm & 7)) * 8); // K-step 1 chunk

    f32x4 acc[8][4] = {};

    // prologue: t0 fully + t1 halves A0,B0 (12 loads/wave); wait t0, keep 4.
    STAGE_A(0, 0, 0); STAGE_B(0, 0, 0);
    STAGE_A(0, 1, 0); STAGE_B(0, 1, 0);
    STAGE_A(1, 0, 1); STAGE_B(1, 0, 1);
    asm volatile("s_waitcnt vmcnt(4)" ::: "memory");
    __builtin_amdgcn_s_barrier();

#pragma unroll 1
    for (int t = 0; t <= 60; t += 2) {
        PHASE(0, 0, 0, STAGE_A(1, 1, t + 1), NOPV);
        PHASE(0, 0, 1, STAGE_B(1, 1, t + 1), NOPV);
        PHASE(0, 1, 0, STAGE_A(0, 0, t + 2), NOPV);
        PHASE(0, 1, 1, STAGE_B(0, 0, t + 2), VM4);
        PHASE(1, 0, 0, STAGE_A(0, 1, t + 2), NOPV);
        PHASE(1, 0, 1, STAGE_B(0, 1, t + 2), NOPV);
        PHASE(1, 1, 0, STAGE_A(1, 0, t + 3), NOPV);
        PHASE(1, 1, 1, STAGE_B(1, 0, t + 3), VM4);
    }
    // peel t = 62 (t63 halves A0/B0 already in flight; finish A1/B1, drain)
    PHASE(0, 0, 0, STAGE_A(1, 1, 63), NOPV);
    PHASE(0, 0, 1, STAGE_B(1, 1, 63), NOPV);
    PHASE(0, 1, 0, NOPV, NOPV);
    PHASE(0, 1, 1, NOPV, VM0);
    PHASE(1, 0, 0, NOPV, NOPV);
    PHASE(1, 0, 1, NOPV, NOPV);
    PHASE(1, 1, 0, NOPV, NOPV);
    PHASE(1, 1, 1, NOPV, NOPV);

    // epilogue: C/D layout col = lane&15 (n), row = quad*4 + r (m89-verified)
    float* Cb = C + (size_t)bat * M_DIM * N_DIM;
#pragma unroll
    for (int a = 0; a < 8; ++a) {
        const int mq = a >> 2, i = a & 3;
        const int m0 = bm0 + mq * 128 + wm * 64 + i * 16 + quad * 4;
#pragma unroll
        for (int b = 0; b < 4; ++b) {
            const int nq = b >> 1, j = b & 1;
            const int n = bn0 + nq * 128 + wn * 32 + j * 16 + fm;
#pragma unroll
            for (int r = 0; r < 4; ++r)
                Cb[(size_t)(m0 + r) * N_DIM + n] = acc[a][b][r];
        }
    }
}

extern "C" void kernel_launch(void* const* d_in, const int* in_sizes, int n_in,
                              void* d_out, int out_size, void* d_ws, size_t ws_size,
                              hipStream_t stream) {
    const float* x    = (const float*)d_in[0];
    const float* vals = (const float*)d_in[1];
    // d_in[2] = row_offsets (structure fixed: row i starts at i*409)
    const int*   cols = (const int*)d_in[3];
    float* out = (float*)d_out;

    // workspace: [ W bf16 : 32 MB ][ Xb bf16 : 64 MB ]
    u16* W  = (u16*)d_ws;
    u16* Xb = (u16*)d_ws + (size_t)M_DIM * K_DIM;

    int n8 = (B_DIM * N_DIM * K_DIM) / 8;  // 4,194,304 threads
    cvt_x<<<dim3(n8 / 256), dim3(256), 0, stream>>>(x, Xb);

    scatter_w<<<dim3(M_DIM), dim3(256), 0, stream>>>(vals, cols, W);

    dim3 grid(N_DIM / 256, M_DIM / 256, B_DIM);
    gemm_bt<<<grid, dim3(512), 0, stream>>>(W, Xb, out);
}

// Round 3
// 460.031 us; speedup vs baseline: 1.1920x; 1.1465x over previous
//
#include <hip/hip_runtime.h>
#include <hip/hip_bf16.h>
#include <stdint.h>

#define M_DIM 4096
#define K_DIM 4096
#define N_DIM 2048
#define B_DIM 4
#define NNZ_PER_ROW 409
#define NNZ_TOT (M_DIM * NNZ_PER_ROW)

typedef unsigned short u16;
typedef short short8 __attribute__((ext_vector_type(8)));
typedef float f32x4 __attribute__((ext_vector_type(4)));

__device__ __forceinline__ u16 f2bf(float f) {
    __hip_bfloat16 h = __float2bfloat16(f);
    u16 s;
    __builtin_memcpy(&s, &h, 2);
    return s;
}

// async global->LDS, 16 bytes per lane; LDS dest = wave-uniform base + lane*16
__device__ __forceinline__ void lds16(const u16* g, u16* l) {
    __builtin_amdgcn_global_load_lds(
        (__attribute__((address_space(1))) void*)g,
        (__attribute__((address_space(3))) void*)l,
        16, 0, 0);
}

// ---------------------------------------------------------------------------
// Kernel 1: x fp32 -> bf16. Each lane: 32 B read (2x float4), 16 B write.
// ---------------------------------------------------------------------------
__global__ void cvt_x(const float* __restrict__ in, u16* __restrict__ out) {
    int i = blockIdx.x * blockDim.x + threadIdx.x;  // 8 elements per thread
    float4 a = reinterpret_cast<const float4*>(in)[2 * i];
    float4 b = reinterpret_cast<const float4*>(in)[2 * i + 1];
    union { u16 u[8]; uint4 v; } o;
    o.u[0] = f2bf(a.x); o.u[1] = f2bf(a.y); o.u[2] = f2bf(a.z); o.u[3] = f2bf(a.w);
    o.u[4] = f2bf(b.x); o.u[5] = f2bf(b.y); o.u[6] = f2bf(b.z); o.u[7] = f2bf(b.w);
    reinterpret_cast<uint4*>(out)[i] = o.v;
}

// ---------------------------------------------------------------------------
// Kernel 2: CSR row -> dense bf16 W row, one block per row.
// fp32 accumulate in LDS (duplicates via atomicAdd, matching .add semantics),
// then fully-coalesced 16B stores. No global memset needed.
// ---------------------------------------------------------------------------
__global__ __launch_bounds__(256) void scatter_w(const float* __restrict__ vals,
                                                 const int* __restrict__ cols,
                                                 u16* __restrict__ W) {
    __shared__ float row[K_DIM];  // 16 KB
    const int t = threadIdx.x;
    const int m = blockIdx.x;
#pragma unroll
    for (int c = t; c < K_DIM; c += 256) row[c] = 0.0f;
    __syncthreads();
    const int base = m * NNZ_PER_ROW;
    for (int j = t; j < NNZ_PER_ROW; j += 256)
        atomicAdd(&row[cols[base + j]], vals[base + j]);
    __syncthreads();
    u16* Wr = W + (size_t)m * K_DIM + t * 16;
#pragma unroll
    for (int h = 0; h < 2; ++h) {
        union { u16 u[8]; uint4 v; } o;
#pragma unroll
        for (int e = 0; e < 8; ++e) o.u[e] = f2bf(row[t * 16 + h * 8 + e]);
        reinterpret_cast<uint4*>(Wr)[h] = o.v;
    }
}

// ---------------------------------------------------------------------------
// Kernel 3: NT GEMM, 256x256 tile, BK=64, 8-phase counted-vmcnt schedule
// with ONCE-PER-K-TILE fragment reads (LDS-BW fix, R1):
//   Quadrant order per K-tile: (0,0) -> (0,1) -> (1,1) -> (1,0).
//     ph1: read A0 (8 b128) + B0 (4)   -> MFMA(0,0)
//     ph2: read B1 (4), reuse A0       -> MFMA(0,1)
//     ph3: read A1 (8), reuse B1       -> MFMA(1,1)
//     ph4: read nothing, reuse A1+B0   -> MFMA(1,0)
//   24 reads/wave/K-tile (vs 48 before): each LDS byte read exactly once.
//   Arithmetic intensity 42.7 FLOP/B -> 96 B/cyc needed at peak (< 128 peak).
//   Read-free map (for stage safety): A0,B0 free after ph1; B1 after ph2;
//   A1 after ph3. Stage schedule unchanged (re-verified vs new read map):
//     p1:(t+1).A1->buf1  p2:(t+1).B1->buf1  p3:(t+2).A0->buf0
//     p4:(t+2).B0->buf0 +vmcnt(4)   [t+1 fully landed before ph5-8 reads]
//     p5:(t+2).A1->buf0  p6:(t+2).B1->buf0  p7:(t+3).A0->buf1
//     p8:(t+3).B0->buf1 +vmcnt(4)   [t+2 fully landed before next-iter reads]
//   Every stage targets a half whose last reader finished >=1 barrier earlier.
//   Row swizzle: chunk c of row r at position c ^ (r&7) (16B chunks), applied
//   via pre-swizzled GLOBAL source + swizzled ds_read offsets; LDS dest linear
//   as global_load_lds requires. Measured 0 bank conflicts.
// ---------------------------------------------------------------------------
#define NOPV ((void)0)
#define VM4 asm volatile("s_waitcnt vmcnt(4)" ::: "memory")
#define VM0 asm volatile("s_waitcnt vmcnt(0)" ::: "memory")

#define STAGE_A(BUF, H, KT) do {                                                  \
    lds16(Ag + (size_t)((H) * 128 +  0) * K_DIM + (size_t)(KT) * 64,              \
          &sA[BUF][(H) * 128 +  0 + wave * 8][0]);                                \
    lds16(Ag + (size_t)((H) * 128 + 64) * K_DIM + (size_t)(KT) * 64,              \
          &sA[BUF][(H) * 128 + 64 + wave * 8][0]);                                \
} while (0)

#define STAGE_B(BUF, H, KT) do {                                                  \
    lds16(Bg + (size_t)((H) * 128 +  0) * K_DIM + (size_t)(KT) * 64,              \
          &sB[BUF][(H) * 128 +  0 + wave * 8][0]);                                \
    lds16(Bg + (size_t)((H) * 128 + 64) * K_DIM + (size_t)(KT) * 64,              \
          &sB[BUF][(H) * 128 + 64 + wave * 8][0]);                                \
} while (0)

// fragment loads into persistent register arrays (all compile-time indexed)
#define DS_A(BUF, MQ) do {                                                        \
    _Pragma("unroll")                                                             \
    for (int i_ = 0; i_ < 4; ++i_) {                                              \
        const u16* p_ = &sA[BUF][(MQ) * 128 + wm * 64 + i_ * 16 + fm][0];         \
        af[i_][0] = *(const short8*)(p_ + c0);                                    \
        af[i_][1] = *(const short8*)(p_ + c1);                                    \
    }                                                                             \
} while (0)

#define DS_B(BUF, NQ, ARR) do {                                                   \
    _Pragma("unroll")                                                             \
    for (int j_ = 0; j_ < 2; ++j_) {                                              \
        const u16* p_ = &sB[BUF][(NQ) * 128 + wn * 32 + j_ * 16 + fm][0];         \
        ARR[j_][0] = *(const short8*)(p_ + c0);                                   \
        ARR[j_][1] = *(const short8*)(p_ + c1);                                   \
    }                                                                             \
} while (0)

// Phase: [ds_read subtile] -> issue stage -> barrier -> lgkm(0) ->
// setprio(1) MFMA x16 setprio(0) -> [vmcnt] -> barrier.
#define PHASE(DS_STMT, STAGE_STMT, MQ, NQ, BARR, WAIT_STMT) do {                  \
    DS_STMT;                                                                      \
    STAGE_STMT;                                                                   \
    asm volatile("" ::: "memory");                                                \
    __builtin_amdgcn_s_barrier();                                                 \
    asm volatile("s_waitcnt lgkmcnt(0)" ::: "memory");                            \
    __builtin_amdgcn_sched_barrier(0);                                            \
    __builtin_amdgcn_s_setprio(1);                                                \
    _Pragma("unroll")                                                             \
    for (int i_ = 0; i_ < 4; ++i_) {                                              \
        _Pragma("unroll")                                                         \
        for (int j_ = 0; j_ < 2; ++j_) {                                          \
            acc[(MQ) * 4 + i_][(NQ) * 2 + j_] =                                   \
                __builtin_amdgcn_mfma_f32_16x16x32_bf16(                          \
                    af[i_][0], BARR[j_][0], acc[(MQ) * 4 + i_][(NQ) * 2 + j_],    \
                    0, 0, 0);                                                     \
            acc[(MQ) * 4 + i_][(NQ) * 2 + j_] =                                   \
                __builtin_amdgcn_mfma_f32_16x16x32_bf16(                          \
                    af[i_][1], BARR[j_][1], acc[(MQ) * 4 + i_][(NQ) * 2 + j_],    \
                    0, 0, 0);                                                     \
        }                                                                         \
    }                                                                             \
    __builtin_amdgcn_s_setprio(0);                                                \
    WAIT_STMT;                                                                    \
    asm volatile("" ::: "memory");                                                \
    __builtin_amdgcn_s_barrier();                                                 \
} while (0)

__global__ __launch_bounds__(512, 2) void gemm_bt(
    const u16* __restrict__ A,
    const u16* __restrict__ Bt,
    float* __restrict__ C) {
    __shared__ __align__(16) u16 sA[2][256][64];  // 64 KB
    __shared__ __align__(16) u16 sB[2][256][64];  // 64 KB

    const int tid  = threadIdx.x;
    const int wave = tid >> 6;
    const int lane = tid & 63;
    const int wm = wave >> 2;     // 0..1 (M)
    const int wn = wave & 3;      // 0..3 (N)

    // XCD-aware bijective swizzle of the 128 (m,n) tiles per batch
    int wg  = blockIdx.y * 8 + blockIdx.x;          // 0..127
    int swz = (wg & 7) * 16 + (wg >> 3);
    const int bn0 = (swz & 7) * 256;
    const int bm0 = (swz >> 3) * 256;
    const int bat = blockIdx.z;

    // staging: lane covers row (lane>>3) of an 8-row group; global 16B chunk
    // is (lane&7) ^ (lane>>3)  [pre-swizzled source, linear LDS dest]
    const int slr = lane >> 3;
    const int slc = ((lane & 7) ^ slr) * 8;
    const u16* Ag = A + (size_t)(bm0 + wave * 8 + slr) * K_DIM + slc;
    const u16* Bg = Bt + (size_t)bat * N_DIM * K_DIM
                      + (size_t)(bn0 + wave * 8 + slr) * K_DIM + slc;

    // fragment decomposition (identical to verified 128^2 kernel)
    const int fm   = lane & 15;
    const int quad = lane >> 4;
    const int c0   = ((quad     ^ (fm & 7)) * 8);   // K-step 0 chunk (elems)
    const int c1   = (((quad + 4) ^ (fm & 7)) * 8); // K-step 1 chunk

    f32x4 acc[8][4] = {};
    short8 af[4][2];    // current A half-tile fragments [i][kstep]  (32 VGPR)
    short8 b0f[2][2];   // B half 0 fragments, live ph1->ph4         (16 VGPR)
    short8 b1f[2][2];   // B half 1 fragments, live ph2->ph3         (16 VGPR)

    // prologue: t0 fully + t1 halves A0,B0 (12 loads/wave); wait t0, keep 4.
    STAGE_A(0, 0, 0); STAGE_B(0, 0, 0);
    STAGE_A(0, 1, 0); STAGE_B(0, 1, 0);
    STAGE_A(1, 0, 1); STAGE_B(1, 0, 1);
    asm volatile("s_waitcnt vmcnt(4)" ::: "memory");
    __builtin_amdgcn_s_barrier();

#pragma unroll 1
    for (int t = 0; t <= 60; t += 2) {
        // buf0 = tile t: quadrants (0,0)(0,1)(1,1)(1,0)
        PHASE(DS_A(0, 0); DS_B(0, 0, b0f), STAGE_A(1, 1, t + 1), 0, 0, b0f, NOPV);
        PHASE(DS_B(0, 1, b1f),             STAGE_B(1, 1, t + 1), 0, 1, b1f, NOPV);
        PHASE(DS_A(0, 1),                  STAGE_A(0, 0, t + 2), 1, 1, b1f, NOPV);
        PHASE(NOPV,                        STAGE_B(0, 0, t + 2), 1, 0, b0f, VM4);
        // buf1 = tile t+1
        PHASE(DS_A(1, 0); DS_B(1, 0, b0f), STAGE_A(0, 1, t + 2), 0, 0, b0f, NOPV);
        PHASE(DS_B(1, 1, b1f),             STAGE_B(0, 1, t + 2), 0, 1, b1f, NOPV);
        PHASE(DS_A(1, 1),                  STAGE_A(1, 0, t + 3), 1, 1, b1f, NOPV);
        PHASE(NOPV,                        STAGE_B(1, 0, t + 3), 1, 0, b0f, VM4);
    }
    // peel t = 62 (t63 halves A0/B0 already in flight; finish A1/B1, drain)
    PHASE(DS_A(0, 0); DS_B(0, 0, b0f), STAGE_A(1, 1, 63), 0, 0, b0f, NOPV);
    PHASE(DS_B(0, 1, b1f),             STAGE_B(1, 1, 63), 0, 1, b1f, NOPV);
    PHASE(DS_A(0, 1),                  NOPV,              1, 1, b1f, NOPV);
    PHASE(NOPV,                        NOPV,              1, 0, b0f, VM0);
    PHASE(DS_A(1, 0); DS_B(1, 0, b0f), NOPV,              0, 0, b0f, NOPV);
    PHASE(DS_B(1, 1, b1f),             NOPV,              0, 1, b1f, NOPV);
    PHASE(DS_A(1, 1),                  NOPV,              1, 1, b1f, NOPV);
    PHASE(NOPV,                        NOPV,              1, 0, b0f, NOPV);

    // epilogue: C/D layout col = lane&15 (n), row = quad*4 + r (m89-verified)
    float* Cb = C + (size_t)bat * M_DIM * N_DIM;
#pragma unroll
    for (int a = 0; a < 8; ++a) {
        const int mq = a >> 2, i = a & 3;
        const int m0 = bm0 + mq * 128 + wm * 64 + i * 16 + quad * 4;
#pragma unroll
        for (int b = 0; b < 4; ++b) {
            const int nq = b >> 1, j = b & 1;
            const int n = bn0 + nq * 128 + wn * 32 + j * 16 + fm;
#pragma unroll
            for (int r = 0; r < 4; ++r)
                Cb[(size_t)(m0 + r) * N_DIM + n] = acc[a][b][r];
        }
    }
}

extern "C" void kernel_launch(void* const* d_in, const int* in_sizes, int n_in,
                              void* d_out, int out_size, void* d_ws, size_t ws_size,
                              hipStream_t stream) {
    const float* x    = (const float*)d_in[0];
    const float* vals = (const float*)d_in[1];
    // d_in[2] = row_offsets (structure fixed: row i starts at i*409)
    const int*   cols = (const int*)d_in[3];
    float* out = (float*)d_out;

    // workspace: [ W bf16 : 32 MB ][ Xb bf16 : 64 MB ]
    u16* W  = (u16*)d_ws;
    u16* Xb = (u16*)d_ws + (size_t)M_DIM * K_DIM;

    int n8 = (B_DIM * N_DIM * K_DIM) / 8;  // 4,194,304 threads
    cvt_x<<<dim3(n8 / 256), dim3(256), 0, stream>>>(x, Xb);

    scatter_w<<<dim3(M_DIM), dim3(256), 0, stream>>>(vals, cols, W);

    dim3 grid(N_DIM / 256, M_DIM / 256, B_DIM);
    gemm_bt<<<grid, dim3(512), 0, stream>>>(W, Xb, out);
}